// Round 1
// baseline (980.693 us; speedup 1.0000x reference)
//
#include <hip/hip_runtime.h>

#define B_ 32
#define L_ 2048
#define C1 512      // conv1 out channels (2C)
#define C2 256      // conv2 out channels
#define KW 15
#define P1 2034     // conv1 valid positions (L-14)
#define NJ 2016     // conv2 positions actually used (pos 2..2017)
#define NSEC 252
#define GOD 256

typedef _Float16 f16;
typedef __attribute__((ext_vector_type(8))) _Float16 f16x8;
typedef __attribute__((ext_vector_type(4))) float f32x4;

// workspace byte offsets
#define WS_Y1T   0ull                       // f16 [32][2034][512]  = 66,650,112 B
#define WS_W2R   66650112ull                // f16 [15][256][512]   =  3,932,160 B
#define WS_E     70582272ull                // f32 [32][256][2016]  = 66,060,288 B
#define WS_V     136642560ull               // f32 [32][2048]       =    262,144 B
#define WS_PART  136904704ull               // f32 [32][8][252]     =    258,048 B
#define WS_ATTN  137162752ull               // f32 [32][252]        =     32,256 B

// ---------------- weight transpose: w2[o][c][k] f32 -> w2r[k][o][c] f16 ----------------
__global__ void k_w2r(const float* __restrict__ w2, f16* __restrict__ w2r) {
    const int n = C2 * C1 * KW;
    for (int idx = blockIdx.x * blockDim.x + threadIdx.x; idx < n; idx += gridDim.x * blockDim.x) {
        int o = idx / (C1 * KW);
        int rem = idx - o * (C1 * KW);
        int c = rem / KW;
        int k = rem - c * KW;
        w2r[((size_t)k * C2 + o) * C1 + c] = (f16)w2[idx];
    }
}

// ---------------- embed + conv1 + relu -> y1t[b][pos][o] f16 ----------------
// grid (8 pos-chunks, 2 channel-halves, 32 b), block 256. thread <-> one channel o.
__global__ __launch_bounds__(256) void k_conv1(const int* __restrict__ seq,
                                               const float* __restrict__ aa_emb,
                                               const float* __restrict__ w1,
                                               const float* __restrict__ b1,
                                               f16* __restrict__ y1t) {
    __shared__ float xs[5][272];
    const int b = blockIdx.z, half = blockIdx.y, chunk = blockIdx.x;
    const int tid = threadIdx.x;
    const int p0 = chunk * 256;

    for (int idx = tid; idx < 270; idx += 256) {
        int l = p0 + idx;
        if (l < L_) {
            int a = seq[b * L_ + l];
#pragma unroll
            for (int e = 0; e < 5; ++e) xs[e][idx] = aa_emb[a * 5 + e];
        } else {
#pragma unroll
            for (int e = 0; e < 5; ++e) xs[e][idx] = 0.f;
        }
    }
    __syncthreads();

    const int o = half * 256 + tid;
    float w[75];
#pragma unroll
    for (int i = 0; i < 75; ++i) w[i] = w1[o * 75 + i];
    const float bias = b1[o];

    for (int pp = 0; pp < 256; pp += 8) {
        if (p0 + pp >= P1) break;
        float acc[8];
#pragma unroll
        for (int u = 0; u < 8; ++u) acc[u] = bias;
#pragma unroll
        for (int e = 0; e < 5; ++e) {
            float xw[22];
#pragma unroll
            for (int t = 0; t < 22; ++t) xw[t] = xs[e][pp + t];
#pragma unroll
            for (int k = 0; k < KW; ++k) {
                float wv = w[e * 15 + k];
#pragma unroll
                for (int u = 0; u < 8; ++u) acc[u] = fmaf(wv, xw[k + u], acc[u]);
            }
        }
#pragma unroll
        for (int u = 0; u < 8; ++u) {
            int pos = p0 + pp + u;
            if (pos < P1)
                y1t[((size_t)b * P1 + pos) * C1 + o] = (f16)fmaxf(acc[u], 0.f);
        }
    }
}

// ---------------- conv2 implicit GEMM, MFMA f16 -> E[b][o][j] f32 (relu) ----------------
// grid (21 n-tiles of 96, 32 b), block 256 = 4 waves. wave-tile 64(M) x 96(N).
// K = 15 taps x 512 ch; K-step 32 = (tap k, c0..c0+32).
__global__ __launch_bounds__(256) void k_conv2(const f16* __restrict__ y1t,
                                               const f16* __restrict__ w2r,
                                               const float* __restrict__ b2,
                                               float* __restrict__ E) {
    const int b = blockIdx.y;
    const int n0 = blockIdx.x * 96;
    const int tid = threadIdx.x;
    const int wave = tid >> 6, lane = tid & 63;
    const int lm = lane & 15, lh = lane >> 4;

    f32x4 acc[4][6];
#pragma unroll
    for (int mf = 0; mf < 4; ++mf)
#pragma unroll
        for (int nf = 0; nf < 6; ++nf) acc[mf][nf] = (f32x4){0.f, 0.f, 0.f, 0.f};

    // per-lane static parts (element units)
    const f16* Abase = w2r + (wave * 64 + lm) * C1 + 8 * lh;                 // + mf*16*C1 + k*C2*C1 + c0
    const f16* Bbase = y1t + ((size_t)b * P1 + n0 + lm + 2) * C1 + 8 * lh;   // + (nf*16 + k)*C1 + c0

#pragma unroll 2
    for (int ks = 0; ks < 240; ++ks) {
        const int k = ks >> 4;
        const int c0 = (ks & 15) << 5;
        f16x8 Af[4], Bf[6];
#pragma unroll
        for (int mf = 0; mf < 4; ++mf)
            Af[mf] = *(const f16x8*)(Abase + k * (C2 * C1) + mf * 16 * C1 + c0);
#pragma unroll
        for (int nf = 0; nf < 6; ++nf)
            Bf[nf] = *(const f16x8*)(Bbase + (nf * 16 + k) * C1 + c0);
#pragma unroll
        for (int mf = 0; mf < 4; ++mf)
#pragma unroll
            for (int nf = 0; nf < 6; ++nf)
                acc[mf][nf] = __builtin_amdgcn_mfma_f32_16x16x32_f16(Af[mf], Bf[nf], acc[mf][nf], 0, 0, 0);
    }

    // epilogue: C/D layout col = lane&15 (n), row = lh*4 + r (m within 16)
#pragma unroll
    for (int mf = 0; mf < 4; ++mf) {
#pragma unroll
        for (int r = 0; r < 4; ++r) {
            int o = wave * 64 + mf * 16 + lh * 4 + r;
            float bias = b2[o];
#pragma unroll
            for (int nf = 0; nf < 6; ++nf) {
                int j = n0 + nf * 16 + lm;
                float val = acc[mf][nf][r] + bias;
                E[((size_t)b * C2 + o) * NJ + j] = fmaxf(val, 0.f);
            }
        }
    }
}

// ---------------- v[b][p] = go_table[goidx[b]] . attn_w[:, p] ----------------
__global__ void k_v(const int* __restrict__ goidx, const float* __restrict__ go_table,
                    const float* __restrict__ attn_w, float* __restrict__ v) {
    const int b = blockIdx.y;
    const int p = blockIdx.x * 256 + threadIdx.x;
    const float* go = go_table + (size_t)goidx[b] * GOD;
    float acc = 0.f;
    for (int g = 0; g < GOD; ++g) acc = fmaf(go[g], attn_w[g * 2048 + p], acc);
    v[b * 2048 + p] = acc;
}

// ---------------- partial energies: partial[b][ch][n] = sum_{c in chunk, r} v[c*8+r]*E[b][c][r*252+n]
__global__ void k_energy(const float* __restrict__ E, const float* __restrict__ v,
                         float* __restrict__ partial) {
    const int b = blockIdx.y, ch = blockIdx.x;
    const int n = threadIdx.x;
    if (n >= NSEC) return;
    float acc = 0.f;
    for (int c = ch * 32; c < ch * 32 + 32; ++c) {
        const float* Erow = E + ((size_t)b * C2 + c) * NJ;
        const float* vp = v + b * 2048 + c * 8;
#pragma unroll
        for (int r = 0; r < 8; ++r) acc = fmaf(vp[r], Erow[r * NSEC + n], acc);
    }
    partial[(b * 8 + ch) * NSEC + n] = acc;
}

// ---------------- sum partials + softmax over 252 -> attn[b][n] ----------------
__global__ void k_softmax(const float* __restrict__ partial, float* __restrict__ attn) {
    const int b = blockIdx.x;
    const int n = threadIdx.x;
    __shared__ float red[256];
    float ev = 0.f;
    float e = -1e30f;
    if (n < NSEC) {
        for (int ch = 0; ch < 8; ++ch) ev += partial[(b * 8 + ch) * NSEC + n];
        e = ev;
    }
    red[n] = e;
    __syncthreads();
    for (int s = 128; s > 0; s >>= 1) {
        if (n < s) red[n] = fmaxf(red[n], red[n + s]);
        __syncthreads();
    }
    float m = red[0];
    __syncthreads();
    float ex = (n < NSEC) ? __expf(ev - m) : 0.f;
    red[n] = ex;
    __syncthreads();
    for (int s = 128; s > 0; s >>= 1) {
        if (n < s) red[n] += red[n + s];
        __syncthreads();
    }
    float inv = 1.f / red[0];
    if (n < NSEC) attn[b * NSEC + n] = ex * inv;
}

// ---------------- ctx[b][p] = sum_i attn[b][i] * E[b][p>>3][(p&7)*252 + i] ----------------
// grid (8, 32), block 256 = 4 waves; one wave computes 64 p's, one p per iteration.
__global__ void k_ctx(const float* __restrict__ E, const float* __restrict__ attn,
                      float* __restrict__ out) {
    const int b = blockIdx.y;
    const int wave = threadIdx.x >> 6, lane = threadIdx.x & 63;
    float a0 = 0.f, a1 = 0.f, a2 = 0.f, a3 = 0.f;
    if (lane < 63) {
        const float* ap = attn + b * NSEC + lane * 4;
        a0 = ap[0]; a1 = ap[1]; a2 = ap[2]; a3 = ap[3];
    }
    const int pbase = blockIdx.x * 256 + wave * 64;
    for (int pi = 0; pi < 64; ++pi) {
        int p = pbase + pi;
        int c = p >> 3, r = p & 7;
        const float* Erow = E + ((size_t)b * C2 + c) * NJ + r * NSEC;
        float s = 0.f;
        if (lane < 63) {
            float2 e0 = *(const float2*)(Erow + lane * 4);
            float2 e1 = *(const float2*)(Erow + lane * 4 + 2);
            s = e0.x * a0 + e0.y * a1 + e1.x * a2 + e1.y * a3;
        }
#pragma unroll
        for (int off = 32; off > 0; off >>= 1) s += __shfl_down(s, off);
        if (lane == 0) out[b * 2048 + p] = s;
    }
}

extern "C" void kernel_launch(void* const* d_in, const int* in_sizes, int n_in,
                              void* d_out, int out_size, void* d_ws, size_t ws_size,
                              hipStream_t stream) {
    const int*   seq      = (const int*)d_in[0];
    const int*   goidx    = (const int*)d_in[1];
    const float* aa_emb   = (const float*)d_in[2];
    const float* w1       = (const float*)d_in[3];
    const float* b1       = (const float*)d_in[4];
    const float* w2       = (const float*)d_in[5];
    const float* b2       = (const float*)d_in[6];
    const float* go_table = (const float*)d_in[7];
    const float* attn_w   = (const float*)d_in[8];
    float* out = (float*)d_out;

    char* ws = (char*)d_ws;
    f16*   y1t     = (f16*)(ws + WS_Y1T);
    f16*   w2r     = (f16*)(ws + WS_W2R);
    float* E       = (float*)(ws + WS_E);
    float* v       = (float*)(ws + WS_V);
    float* partial = (float*)(ws + WS_PART);
    float* attn    = (float*)(ws + WS_ATTN);

    hipLaunchKernelGGL(k_w2r,     dim3(512),        dim3(256), 0, stream, w2, w2r);
    hipLaunchKernelGGL(k_conv1,   dim3(8, 2, B_),   dim3(256), 0, stream, seq, aa_emb, w1, b1, y1t);
    hipLaunchKernelGGL(k_conv2,   dim3(21, B_),     dim3(256), 0, stream, y1t, w2r, b2, E);
    hipLaunchKernelGGL(k_v,       dim3(8, B_),      dim3(256), 0, stream, goidx, go_table, attn_w, v);
    hipLaunchKernelGGL(k_energy,  dim3(8, B_),      dim3(256), 0, stream, E, v, partial);
    hipLaunchKernelGGL(k_softmax, dim3(B_),         dim3(256), 0, stream, partial, attn);
    hipLaunchKernelGGL(k_ctx,     dim3(8, B_),      dim3(256), 0, stream, E, attn, out);
}

// Round 2
// 348.458 us; speedup vs baseline: 2.8144x; 2.8144x over previous
//
#include <hip/hip_runtime.h>

#define B_ 32
#define L_ 2048
#define C1 512      // conv1 out channels (2C)
#define C2 256      // conv2 out channels
#define KW 15
#define P1 2034     // conv1 valid positions (L-14)
#define NJ 2016     // conv2 positions actually used (pos 2..2017)
#define NSEC 252
#define GOD 256

typedef _Float16 f16;
typedef __attribute__((ext_vector_type(8))) _Float16 f16x8;
typedef __attribute__((ext_vector_type(4))) float f32x4;

// workspace byte offsets
#define WS_Y1T   0ull                       // f16 [32][2034][512]  = 66,650,112 B
#define WS_W2R   66650112ull                // f16 [15][256][512]   =  3,932,160 B
#define WS_E     70582272ull                // f32 [32][256][2016]  = 66,060,288 B
#define WS_V     136642560ull               // f32 [32][2048]       =    262,144 B
#define WS_PART  136904704ull               // f32 [32][8][252]     =    258,048 B
#define WS_ATTN  137162752ull               // f32 [32][252]        =     32,256 B

__device__ __forceinline__ void gl16(const f16* g, f16* l) {
    __builtin_amdgcn_global_load_lds((const __attribute__((address_space(1))) char*)(g),
                                     (__attribute__((address_space(3))) char*)(l), 16, 0, 0);
}

// ---------------- weight transpose: w2[o][c][k] f32 -> w2r[k][o][c] f16 ----------------
__global__ void k_w2r(const float* __restrict__ w2, f16* __restrict__ w2r) {
    const int n = C2 * C1 * KW;
    for (int idx = blockIdx.x * blockDim.x + threadIdx.x; idx < n; idx += gridDim.x * blockDim.x) {
        int o = idx / (C1 * KW);
        int rem = idx - o * (C1 * KW);
        int c = rem / KW;
        int k = rem - c * KW;
        w2r[((size_t)k * C2 + o) * C1 + c] = (f16)w2[idx];
    }
}

// ---------------- embed + conv1 + relu -> y1t[b][pos][o] f16 ----------------
__global__ __launch_bounds__(256) void k_conv1(const int* __restrict__ seq,
                                               const float* __restrict__ aa_emb,
                                               const float* __restrict__ w1,
                                               const float* __restrict__ b1,
                                               f16* __restrict__ y1t) {
    __shared__ float xs[5][272];
    const int b = blockIdx.z, half = blockIdx.y, chunk = blockIdx.x;
    const int tid = threadIdx.x;
    const int p0 = chunk * 256;

    for (int idx = tid; idx < 270; idx += 256) {
        int l = p0 + idx;
        if (l < L_) {
            int a = seq[b * L_ + l];
#pragma unroll
            for (int e = 0; e < 5; ++e) xs[e][idx] = aa_emb[a * 5 + e];
        } else {
#pragma unroll
            for (int e = 0; e < 5; ++e) xs[e][idx] = 0.f;
        }
    }
    __syncthreads();

    const int o = half * 256 + tid;
    float w[75];
#pragma unroll
    for (int i = 0; i < 75; ++i) w[i] = w1[o * 75 + i];
    const float bias = b1[o];

    for (int pp = 0; pp < 256; pp += 8) {
        if (p0 + pp >= P1) break;
        float acc[8];
#pragma unroll
        for (int u = 0; u < 8; ++u) acc[u] = bias;
#pragma unroll
        for (int e = 0; e < 5; ++e) {
            float xw[22];
#pragma unroll
            for (int t = 0; t < 22; ++t) xw[t] = xs[e][pp + t];
#pragma unroll
            for (int k = 0; k < KW; ++k) {
                float wv = w[e * 15 + k];
#pragma unroll
                for (int u = 0; u < 8; ++u) acc[u] = fmaf(wv, xw[k + u], acc[u]);
            }
        }
#pragma unroll
        for (int u = 0; u < 8; ++u) {
            int pos = p0 + pp + u;
            if (pos < P1)
                y1t[((size_t)b * P1 + pos) * C1 + o] = (f16)fmaxf(acc[u], 0.f);
        }
    }
}

// ---------------- conv2 implicit GEMM, LDS double-buffered MFMA f16 ----------------
// grid (8 n-tiles of 256, 32 b), block 512 = 8 waves (2M x 4N), wave tile 128x64.
// K = 15 taps x 512 ch, processed as 8 c-chunks of 64 x 15 taps; phase = (cc,k).
// A (weights) tile [256][64] staged per phase (dbuf 2x32KB); B (y1) tile
// [320 rows][64] staged per c-chunk (dbuf 2x40KB). Both XOR-swizzled
// (byte ^= (row&7)<<4) with inverse-swizzled global source (linear LDS dest).
__global__ __launch_bounds__(512, 2) void k_conv2(const f16* __restrict__ y1t,
                                                  const f16* __restrict__ w2r,
                                                  const float* __restrict__ b2,
                                                  float* __restrict__ E) {
    __shared__ f16 As[2][16384];   // 2 x 32 KB
    __shared__ f16 Bs[2][20480];   // 2 x 40 KB
    const int b = blockIdx.y;
    const int n0 = blockIdx.x << 8;
    const int tid = threadIdx.x;
    const int wave = tid >> 6, lane = tid & 63;
    const int lm = lane & 15, lh = lane >> 4;
    const int wm = wave >> 2, wn = wave & 3;

    const size_t ybase = (size_t)b * P1 + n0 + 2;
    const int qw = wave * 1024 + lane * 16;   // per-thread byte offset within a round

    f32x4 acc[8][4];
#pragma unroll
    for (int mf = 0; mf < 8; ++mf)
#pragma unroll
        for (int nf = 0; nf < 4; ++nf) acc[mf][nf] = (f32x4){0.f, 0.f, 0.f, 0.f};

#define STAGE_A(buf, cc, k)                                                       \
    {                                                                             \
        _Pragma("unroll")                                                         \
        for (int r = 0; r < 4; ++r) {                                             \
            int q = r * 8192 + qw;                                                \
            int o = q >> 7;                                                       \
            int sl = ((q >> 4) & 7) ^ (o & 7);                                    \
            const f16* g = w2r + (size_t)(k) * 131072 + o * 512 + (cc) * 64 + sl * 8; \
            f16* l = (f16*)As[buf] + ((r * 8192 + wave * 1024) >> 1);             \
            gl16(g, l);                                                           \
        }                                                                         \
    }
#define STAGE_B(buf, cc)                                                          \
    {                                                                             \
        _Pragma("unroll")                                                         \
        for (int r = 0; r < 5; ++r) {                                             \
            int q = r * 8192 + qw;                                                \
            int row = q >> 7;                                                     \
            int sl = ((q >> 4) & 7) ^ (row & 7);                                  \
            const f16* g = y1t + (ybase + row) * 512 + (cc) * 64 + sl * 8;        \
            f16* l = (f16*)Bs[buf] + ((r * 8192 + wave * 1024) >> 1);             \
            gl16(g, l);                                                           \
        }                                                                         \
    }

    // prologue
    STAGE_A(0, 0, 0);
    STAGE_B(0, 0);
    __syncthreads();

    const int A0 = wm * 16384 + lm * 128;
    const int xa = (lm & 7) << 4;
    const int swA0 = (lh * 16) ^ xa;
    const int swA1 = (64 + lh * 16) ^ xa;
    const int bnbase = wn * 64 + lm;

    int cc = 0, k = 0;
    for (int p = 0; p < 120; ++p) {
        const int ab = p & 1, bb = cc & 1;
        // next-phase indices
        int kn = k + 1, ccn = cc;
        if (kn == 15) { kn = 0; ccn = cc + 1; }
        // issue next-phase staging first (loads fly during compute)
        if (p < 119) {
            STAGE_A((p + 1) & 1, ccn, kn);
            if (kn == 0) STAGE_B(ccn & 1, ccn);
        }

        const char* Ab = (const char*)As[ab];
        const char* Bb = (const char*)Bs[bb];
        const int brow = bnbase + k;
        const int B0 = brow * 128;
        const int xb = (brow & 7) << 4;
        const int swB0 = (lh * 16) ^ xb;
        const int swB1 = (64 + lh * 16) ^ xb;

        f16x8 av[8], bv[4];
        // cs = 0
#pragma unroll
        for (int mf = 0; mf < 8; ++mf) av[mf] = *(const f16x8*)(Ab + A0 + mf * 2048 + swA0);
#pragma unroll
        for (int nf = 0; nf < 4; ++nf) bv[nf] = *(const f16x8*)(Bb + B0 + nf * 2048 + swB0);
#pragma unroll
        for (int mf = 0; mf < 8; ++mf)
#pragma unroll
            for (int nf = 0; nf < 4; ++nf)
                acc[mf][nf] = __builtin_amdgcn_mfma_f32_16x16x32_f16(av[mf], bv[nf], acc[mf][nf], 0, 0, 0);
        // cs = 1
#pragma unroll
        for (int mf = 0; mf < 8; ++mf) av[mf] = *(const f16x8*)(Ab + A0 + mf * 2048 + swA1);
#pragma unroll
        for (int nf = 0; nf < 4; ++nf) bv[nf] = *(const f16x8*)(Bb + B0 + nf * 2048 + swB1);
#pragma unroll
        for (int mf = 0; mf < 8; ++mf)
#pragma unroll
            for (int nf = 0; nf < 4; ++nf)
                acc[mf][nf] = __builtin_amdgcn_mfma_f32_16x16x32_f16(av[mf], bv[nf], acc[mf][nf], 0, 0, 0);

        __syncthreads();
        k = kn; cc = ccn;
    }

    // epilogue: C/D layout col = lane&15 (n), row = lh*4 + r (m within 16)
#pragma unroll
    for (int mf = 0; mf < 8; ++mf) {
        const int o = wm * 128 + mf * 16 + lh * 4;
#pragma unroll
        for (int r = 0; r < 4; ++r) {
            float bias = b2[o + r];
#pragma unroll
            for (int nf = 0; nf < 4; ++nf) {
                int j = n0 + wn * 64 + nf * 16 + lm;
                if (j < NJ)
                    E[((size_t)b * C2 + (o + r)) * NJ + j] = fmaxf(acc[mf][nf][r] + bias, 0.f);
            }
        }
    }
#undef STAGE_A
#undef STAGE_B
}

// ---------------- v[b][p] = go_table[goidx[b]] . attn_w[:, p] ----------------
__global__ void k_v(const int* __restrict__ goidx, const float* __restrict__ go_table,
                    const float* __restrict__ attn_w, float* __restrict__ v) {
    const int b = blockIdx.y;
    const int p = blockIdx.x * 256 + threadIdx.x;
    const float* go = go_table + (size_t)goidx[b] * GOD;
    float acc = 0.f;
    for (int g = 0; g < GOD; ++g) acc = fmaf(go[g], attn_w[g * 2048 + p], acc);
    v[b * 2048 + p] = acc;
}

// ---------------- partial energies ----------------
__global__ void k_energy(const float* __restrict__ E, const float* __restrict__ v,
                         float* __restrict__ partial) {
    const int b = blockIdx.y, ch = blockIdx.x;
    const int n = threadIdx.x;
    if (n >= NSEC) return;
    float acc = 0.f;
    for (int c = ch * 32; c < ch * 32 + 32; ++c) {
        const float* Erow = E + ((size_t)b * C2 + c) * NJ;
        const float* vp = v + b * 2048 + c * 8;
#pragma unroll
        for (int r = 0; r < 8; ++r) acc = fmaf(vp[r], Erow[r * NSEC + n], acc);
    }
    partial[(b * 8 + ch) * NSEC + n] = acc;
}

// ---------------- sum partials + softmax over 252 -> attn[b][n] ----------------
__global__ void k_softmax(const float* __restrict__ partial, float* __restrict__ attn) {
    const int b = blockIdx.x;
    const int n = threadIdx.x;
    __shared__ float red[256];
    float ev = 0.f;
    float e = -1e30f;
    if (n < NSEC) {
        for (int ch = 0; ch < 8; ++ch) ev += partial[(b * 8 + ch) * NSEC + n];
        e = ev;
    }
    red[n] = e;
    __syncthreads();
    for (int s = 128; s > 0; s >>= 1) {
        if (n < s) red[n] = fmaxf(red[n], red[n + s]);
        __syncthreads();
    }
    float m = red[0];
    __syncthreads();
    float ex = (n < NSEC) ? __expf(ev - m) : 0.f;
    red[n] = ex;
    __syncthreads();
    for (int s = 128; s > 0; s >>= 1) {
        if (n < s) red[n] += red[n + s];
        __syncthreads();
    }
    float inv = 1.f / red[0];
    if (n < NSEC) attn[b * NSEC + n] = ex * inv;
}

// ---------------- ctx ----------------
__global__ void k_ctx(const float* __restrict__ E, const float* __restrict__ attn,
                      float* __restrict__ out) {
    const int b = blockIdx.y;
    const int wave = threadIdx.x >> 6, lane = threadIdx.x & 63;
    float a0 = 0.f, a1 = 0.f, a2 = 0.f, a3 = 0.f;
    if (lane < 63) {
        const float* ap = attn + b * NSEC + lane * 4;
        a0 = ap[0]; a1 = ap[1]; a2 = ap[2]; a3 = ap[3];
    }
    const int pbase = blockIdx.x * 256 + wave * 64;
    for (int pi = 0; pi < 64; ++pi) {
        int p = pbase + pi;
        int c = p >> 3, r = p & 7;
        const float* Erow = E + ((size_t)b * C2 + c) * NJ + r * NSEC;
        float s = 0.f;
        if (lane < 63) {
            float2 e0 = *(const float2*)(Erow + lane * 4);
            float2 e1 = *(const float2*)(Erow + lane * 4 + 2);
            s = e0.x * a0 + e0.y * a1 + e1.x * a2 + e1.y * a3;
        }
#pragma unroll
        for (int off = 32; off > 0; off >>= 1) s += __shfl_down(s, off);
        if (lane == 0) out[b * 2048 + p] = s;
    }
}

extern "C" void kernel_launch(void* const* d_in, const int* in_sizes, int n_in,
                              void* d_out, int out_size, void* d_ws, size_t ws_size,
                              hipStream_t stream) {
    const int*   seq      = (const int*)d_in[0];
    const int*   goidx    = (const int*)d_in[1];
    const float* aa_emb   = (const float*)d_in[2];
    const float* w1       = (const float*)d_in[3];
    const float* b1       = (const float*)d_in[4];
    const float* w2       = (const float*)d_in[5];
    const float* b2       = (const float*)d_in[6];
    const float* go_table = (const float*)d_in[7];
    const float* attn_w   = (const float*)d_in[8];
    float* out = (float*)d_out;

    char* ws = (char*)d_ws;
    f16*   y1t     = (f16*)(ws + WS_Y1T);
    f16*   w2r     = (f16*)(ws + WS_W2R);
    float* E       = (float*)(ws + WS_E);
    float* v       = (float*)(ws + WS_V);
    float* partial = (float*)(ws + WS_PART);
    float* attn    = (float*)(ws + WS_ATTN);

    hipLaunchKernelGGL(k_w2r,     dim3(512),        dim3(256), 0, stream, w2, w2r);
    hipLaunchKernelGGL(k_conv1,   dim3(8, 2, B_),   dim3(256), 0, stream, seq, aa_emb, w1, b1, y1t);
    hipLaunchKernelGGL(k_conv2,   dim3(8, B_),      dim3(512), 0, stream, y1t, w2r, b2, E);
    hipLaunchKernelGGL(k_v,       dim3(8, B_),      dim3(256), 0, stream, goidx, go_table, attn_w, v);
    hipLaunchKernelGGL(k_energy,  dim3(8, B_),      dim3(256), 0, stream, E, v, partial);
    hipLaunchKernelGGL(k_softmax, dim3(B_),         dim3(256), 0, stream, partial, attn);
    hipLaunchKernelGGL(k_ctx,     dim3(8, B_),      dim3(256), 0, stream, E, attn, out);
}

// Round 3
// 327.890 us; speedup vs baseline: 2.9909x; 1.0627x over previous
//
#include <hip/hip_runtime.h>

#define B_ 32
#define L_ 2048
#define C1 512      // conv1 out channels (2C)
#define C2 256      // conv2 out channels
#define KW 15
#define P1 2034     // conv1 valid positions (L-14)
#define NJ 2016     // conv2 positions actually used (pos 2..2017)
#define NSEC 252
#define GOD 256

typedef _Float16 f16;
typedef __attribute__((ext_vector_type(4))) _Float16 f16x4;
typedef __attribute__((ext_vector_type(8))) _Float16 f16x8;
typedef __attribute__((ext_vector_type(4))) float f32x4;

// workspace byte offsets
#define WS_Y1T   0ull                       // f16 [32][2034][512]  = 66,650,112 B
#define WS_W2R   66650112ull                // f16 [15][256][512]   =  3,932,160 B
#define WS_W1R   70582272ull                // f16 [512][104]       =    106,496 B
#define WS_E     70688768ull                // f32 [32][256][2016]  = 66,060,288 B
#define WS_V     136749056ull               // f32 [32][2048]       =    262,144 B
#define WS_EN    137011200ull               // f32 [32][252]        =     32,256 B
#define WS_ATTN  137043456ull               // f32 [32][252]        =     32,256 B

__device__ __forceinline__ void gl16(const f16* g, f16* l) {
    __builtin_amdgcn_global_load_lds((const __attribute__((address_space(1))) char*)(g),
                                     (__attribute__((address_space(3))) char*)(l), 16, 0, 0);
}

// ---------------- w2[o][c][k] f32 -> w2r[k][o][c] f16 ----------------
__global__ void k_w2r(const float* __restrict__ w2, f16* __restrict__ w2r) {
    const int n = C2 * C1 * KW;
    for (int idx = blockIdx.x * blockDim.x + threadIdx.x; idx < n; idx += gridDim.x * blockDim.x) {
        int o = idx / (C1 * KW);
        int rem = idx - o * (C1 * KW);
        int c = rem / KW;
        int k = rem - c * KW;
        w2r[((size_t)k * C2 + o) * C1 + c] = (f16)w2[idx];
    }
}

// ---------------- w1[o][e][k] f32 -> w1r[o][104] f16, col = e*16+k, zero-padded ----------------
__global__ void k_w1r(const float* __restrict__ w1, f16* __restrict__ w1r) {
    const int n = C1 * 104;
    for (int idx = blockIdx.x * blockDim.x + threadIdx.x; idx < n; idx += gridDim.x * blockDim.x) {
        int o = idx / 104;
        int col = idx - o * 104;
        int e = col >> 4, k = col & 15;
        float val = (e < 5 && k < 15) ? w1[o * 75 + e * 15 + k] : 0.f;
        w1r[idx] = (f16)val;
    }
}

// ---------------- conv1 as MFMA implicit GEMM -> y1t[b][pos][o] f16 ----------------
// grid (32 pos-tiles of 64, 2 o-halves of 256, 32 b), block 256 = 4 waves.
// Per block: A = w1r[o0..o0+255][104] staged to LDS (52 KB), B[j][kk] built from
// embedded seq (13 KB). K = 96 (3 MFMA k-steps); wave-tile 64(M) x 64(N).
__global__ __launch_bounds__(256) void k_conv1(const int* __restrict__ seq,
                                               const float* __restrict__ aa_emb,
                                               const f16* __restrict__ w1r,
                                               const float* __restrict__ b1,
                                               f16* __restrict__ y1t) {
    __shared__ f16 Aw[256 * 104];   // 52 KB, rows 208 B
    __shared__ f16 Bx[64 * 104];    // 13 KB, rows 208 B
    __shared__ float xs[5][80];
    const int b = blockIdx.z, o0 = blockIdx.y * 256, pos0 = blockIdx.x * 64;
    const int tid = threadIdx.x;
    const int wave = tid >> 6, lane = tid & 63;
    const int lm = lane & 15, lh = lane >> 4;

    // stage A: 53248 B = 13 x 16B per thread, linear
#pragma unroll
    for (int r = 0; r < 13; ++r) {
        int q = r * 4096 + wave * 1024 + lane * 16;
        gl16(w1r + o0 * 104 + (q >> 1), Aw + (q >> 1));
    }
    // embed x
    if (tid < 79) {
        int l = pos0 + tid;
        if (l < L_) {
            int a = seq[b * L_ + l];
#pragma unroll
            for (int e = 0; e < 5; ++e) xs[e][tid] = aa_emb[a * 5 + e];
        } else {
#pragma unroll
            for (int e = 0; e < 5; ++e) xs[e][tid] = 0.f;
        }
    }
    __syncthreads();
    // build B: Bx[j][e*16+k] = xs[e][j+k]
    for (int idx = tid; idx < 64 * 104; idx += 256) {
        int j = idx / 104, col = idx - j * 104;
        int e = col >> 4, k = col & 15;
        Bx[idx] = (e < 5 && k < 15) ? (f16)xs[e][j + k] : (f16)0.f;
    }
    __syncthreads();

    f32x4 acc[4][4];
#pragma unroll
    for (int mf = 0; mf < 4; ++mf)
#pragma unroll
        for (int nf = 0; nf < 4; ++nf) acc[mf][nf] = (f32x4){0.f, 0.f, 0.f, 0.f};

    const char* Ab = (const char*)Aw + (wave * 64 + lm) * 208 + lh * 16;
    const char* Bb = (const char*)Bx + lm * 208 + lh * 16;
#pragma unroll
    for (int ks = 0; ks < 3; ++ks) {
        f16x8 av[4], bv[4];
#pragma unroll
        for (int mf = 0; mf < 4; ++mf) av[mf] = *(const f16x8*)(Ab + mf * 16 * 208 + ks * 64);
#pragma unroll
        for (int nf = 0; nf < 4; ++nf) bv[nf] = *(const f16x8*)(Bb + nf * 16 * 208 + ks * 64);
#pragma unroll
        for (int mf = 0; mf < 4; ++mf)
#pragma unroll
            for (int nf = 0; nf < 4; ++nf)
                acc[mf][nf] = __builtin_amdgcn_mfma_f32_16x16x32_f16(av[mf], bv[nf], acc[mf][nf], 0, 0, 0);
    }

    // epilogue: col = lm (j), row = lh*4+r (m within 16); 4 consecutive o -> f16x4 store
#pragma unroll
    for (int nf = 0; nf < 4; ++nf) {
        int pos = pos0 + nf * 16 + lm;
        if (pos >= P1) continue;
#pragma unroll
        for (int mf = 0; mf < 4; ++mf) {
            int ob = wave * 64 + mf * 16 + lh * 4;
            f16x4 st;
#pragma unroll
            for (int r = 0; r < 4; ++r)
                st[r] = (f16)fmaxf(acc[mf][nf][r] + b1[o0 + ob + r], 0.f);
            *(f16x4*)(y1t + ((size_t)b * P1 + pos) * C1 + o0 + ob) = st;
        }
    }
}

// ---------------- conv2 implicit GEMM + fused energy partials ----------------
// grid (16 n-tiles of 128, 2 o-halves of 128, 32 b), block 256 = 4 waves (2m x 2n),
// wave tile 64x64. LDS 72 KB -> 2 blocks/CU (two independent barrier domains).
// K = 8 c-chunks of 64 x 15 taps = 120 phases. A dbuf per phase; B dbuf per c-chunk,
// prefetch issued at k==0 (15 phases of slack). XOR-swizzle byte^=((row&7)<<4).
__global__ __launch_bounds__(256) void k_conv2(const f16* __restrict__ y1t,
                                               const f16* __restrict__ w2r,
                                               const float* __restrict__ b2,
                                               const float* __restrict__ v,
                                               float* __restrict__ E,
                                               float* __restrict__ energies) {
    __shared__ f16 As[2][8192];    // 2 x 16 KB : [128 o][64 c]
    __shared__ f16 Bs[2][10240];   // 2 x 20 KB : [160 rows][64 c]
    const int b = blockIdx.z;
    const int o0 = blockIdx.y << 7;
    const int n0 = blockIdx.x << 7;
    const int tid = threadIdx.x;
    const int wave = tid >> 6, lane = tid & 63;
    const int lm = lane & 15, lh = lane >> 4;
    const int wm = wave >> 1, wn = wave & 1;

    const size_t ybase = (size_t)b * P1 + n0 + 2;

    f32x4 acc[4][4];
#pragma unroll
    for (int mf = 0; mf < 4; ++mf)
#pragma unroll
        for (int nf = 0; nf < 4; ++nf) acc[mf][nf] = (f32x4){0.f, 0.f, 0.f, 0.f};

#define STAGE_A(buf, cc, k)                                                           \
    {                                                                                 \
        _Pragma("unroll")                                                             \
        for (int r = 0; r < 4; ++r) {                                                 \
            int q = r * 4096 + wave * 1024 + lane * 16;                               \
            int o = q >> 7;                                                           \
            int sl = ((q >> 4) & 7) ^ (o & 7);                                        \
            const f16* g = w2r + (size_t)(k) * (C2 * C1) + (o0 + o) * C1 + (cc) * 64 + sl * 8; \
            gl16(g, (f16*)As[buf] + (q >> 1));                                        \
        }                                                                             \
    }
#define STAGE_B(buf, cc)                                                              \
    {                                                                                 \
        _Pragma("unroll")                                                             \
        for (int r = 0; r < 5; ++r) {                                                 \
            int q = r * 4096 + wave * 1024 + lane * 16;                               \
            int row = q >> 7;                                                         \
            int sl = ((q >> 4) & 7) ^ (row & 7);                                      \
            const f16* g = y1t + (ybase + row) * C1 + (cc) * 64 + sl * 8;             \
            gl16(g, (f16*)Bs[buf] + (q >> 1));                                        \
        }                                                                             \
    }

    STAGE_A(0, 0, 0);
    STAGE_B(0, 0);
    __syncthreads();

    const int xa = (lm & 7) << 4;
    const int swA0 = (lh * 16) ^ xa;
    const int swA1 = (64 + lh * 16) ^ xa;
    const int Abase = (wm * 64 + lm) * 128;

    for (int cc = 0; cc < 8; ++cc) {
        for (int k = 0; k < 15; ++k) {
            const int ab = (cc + k) & 1;
            if (k == 0 && cc < 7) STAGE_B((cc + 1) & 1, cc + 1);
            if (!(cc == 7 && k == 14)) {
                int kn = k + 1, ccn = cc;
                if (kn == 15) { kn = 0; ccn = cc + 1; }
                STAGE_A(ab ^ 1, ccn, kn);
            }

            const char* Ab = (const char*)As[ab];
            const char* Bb = (const char*)Bs[cc & 1];
            const int brow = wn * 64 + lm + k;
            const int Bbase = brow * 128;
            const int xb = (brow & 7) << 4;
            const int swB0 = (lh * 16) ^ xb;
            const int swB1 = (64 + lh * 16) ^ xb;

            f16x8 av[4], bv[4];
#pragma unroll
            for (int mf = 0; mf < 4; ++mf) av[mf] = *(const f16x8*)(Ab + Abase + mf * 2048 + swA0);
#pragma unroll
            for (int nf = 0; nf < 4; ++nf) bv[nf] = *(const f16x8*)(Bb + Bbase + nf * 2048 + swB0);
#pragma unroll
            for (int mf = 0; mf < 4; ++mf)
#pragma unroll
                for (int nf = 0; nf < 4; ++nf)
                    acc[mf][nf] = __builtin_amdgcn_mfma_f32_16x16x32_f16(av[mf], bv[nf], acc[mf][nf], 0, 0, 0);
#pragma unroll
            for (int mf = 0; mf < 4; ++mf) av[mf] = *(const f16x8*)(Ab + Abase + mf * 2048 + swA1);
#pragma unroll
            for (int nf = 0; nf < 4; ++nf) bv[nf] = *(const f16x8*)(Bb + Bbase + nf * 2048 + swB1);
#pragma unroll
            for (int mf = 0; mf < 4; ++mf)
#pragma unroll
                for (int nf = 0; nf < 4; ++nf)
                    acc[mf][nf] = __builtin_amdgcn_mfma_f32_16x16x32_f16(av[mf], bv[nf], acc[mf][nf], 0, 0, 0);

            __syncthreads();
        }
    }

    // epilogue: E store (bias+relu) + fused energy partials
    const float* vb = v + b * 2048;
#pragma unroll
    for (int nf = 0; nf < 4; ++nf) {
        const int j = n0 + wn * 64 + nf * 16 + lm;
        if (j >= NJ) continue;
        const int jq = j / NSEC;
        const int jm = j - jq * NSEC;
        float esum = 0.f;
#pragma unroll
        for (int mf = 0; mf < 4; ++mf) {
            const int ob = o0 + wm * 64 + mf * 16 + lh * 4;
#pragma unroll
            for (int r = 0; r < 4; ++r) {
                float val = fmaxf(acc[mf][nf][r] + b2[ob + r], 0.f);
                E[((size_t)b * C2 + ob + r) * NJ + j] = val;
                esum = fmaf(val, vb[(ob + r) * 8 + jq], esum);
            }
        }
        atomicAdd(&energies[b * NSEC + jm], esum);
    }
#undef STAGE_A
#undef STAGE_B
}

// ---------------- v[b][p] = go_table[goidx[b]] . attn_w[:, p] ----------------
__global__ void k_v(const int* __restrict__ goidx, const float* __restrict__ go_table,
                    const float* __restrict__ attn_w, float* __restrict__ v) {
    const int b = blockIdx.y;
    const int p = blockIdx.x * 256 + threadIdx.x;
    const float* go = go_table + (size_t)goidx[b] * GOD;
    float acc = 0.f;
    for (int g = 0; g < GOD; ++g) acc = fmaf(go[g], attn_w[g * 2048 + p], acc);
    v[b * 2048 + p] = acc;
}

// ---------------- softmax over 252 (energies already summed via atomics) ----------------
__global__ void k_softmax(const float* __restrict__ energies, float* __restrict__ attn) {
    const int b = blockIdx.x;
    const int n = threadIdx.x;
    __shared__ float red[256];
    float ev = 0.f;
    float e = -1e30f;
    if (n < NSEC) { ev = energies[b * NSEC + n]; e = ev; }
    red[n] = e;
    __syncthreads();
    for (int s = 128; s > 0; s >>= 1) {
        if (n < s) red[n] = fmaxf(red[n], red[n + s]);
        __syncthreads();
    }
    float m = red[0];
    __syncthreads();
    float ex = (n < NSEC) ? __expf(ev - m) : 0.f;
    red[n] = ex;
    __syncthreads();
    for (int s = 128; s > 0; s >>= 1) {
        if (n < s) red[n] += red[n + s];
        __syncthreads();
    }
    float inv = 1.f / red[0];
    if (n < NSEC) attn[b * NSEC + n] = ex * inv;
}

// ---------------- ctx[b][c*8+r] = sum_i attn[b][i] * E[b][c][r*252+i] ----------------
// grid (64, 32), block 256 = 4 waves; one wave per channel c, 8 shuffle-reduces.
__global__ void k_ctx(const float* __restrict__ E, const float* __restrict__ attn,
                      float* __restrict__ out) {
    const int b = blockIdx.y;
    const int wave = threadIdx.x >> 6, lane = threadIdx.x & 63;
    const int c = blockIdx.x * 4 + wave;
    float a0 = 0.f, a1 = 0.f, a2 = 0.f, a3 = 0.f;
    if (lane < 63) {
        const float* ap = attn + b * NSEC + lane * 4;
        a0 = ap[0]; a1 = ap[1]; a2 = ap[2]; a3 = ap[3];
    }
    const float* Er = E + ((size_t)b * C2 + c) * NJ;
#pragma unroll
    for (int r = 0; r < 8; ++r) {
        float s = 0.f;
        if (lane < 63) {
            float2 e0 = *(const float2*)(Er + r * NSEC + lane * 4);
            float2 e1 = *(const float2*)(Er + r * NSEC + lane * 4 + 2);
            s = e0.x * a0 + e0.y * a1 + e1.x * a2 + e1.y * a3;
        }
#pragma unroll
        for (int off = 32; off > 0; off >>= 1) s += __shfl_down(s, off);
        if (lane == 0) out[b * 2048 + c * 8 + r] = s;
    }
}

extern "C" void kernel_launch(void* const* d_in, const int* in_sizes, int n_in,
                              void* d_out, int out_size, void* d_ws, size_t ws_size,
                              hipStream_t stream) {
    const int*   seq      = (const int*)d_in[0];
    const int*   goidx    = (const int*)d_in[1];
    const float* aa_emb   = (const float*)d_in[2];
    const float* w1       = (const float*)d_in[3];
    const float* b1       = (const float*)d_in[4];
    const float* w2       = (const float*)d_in[5];
    const float* b2       = (const float*)d_in[6];
    const float* go_table = (const float*)d_in[7];
    const float* attn_w   = (const float*)d_in[8];
    float* out = (float*)d_out;

    char* ws = (char*)d_ws;
    f16*   y1t      = (f16*)(ws + WS_Y1T);
    f16*   w2r      = (f16*)(ws + WS_W2R);
    f16*   w1r      = (f16*)(ws + WS_W1R);
    float* E        = (float*)(ws + WS_E);
    float* v        = (float*)(ws + WS_V);
    float* energies = (float*)(ws + WS_EN);
    float* attn     = (float*)(ws + WS_ATTN);

    hipMemsetAsync(energies, 0, B_ * NSEC * sizeof(float), stream);
    hipLaunchKernelGGL(k_w2r,     dim3(512),         dim3(256), 0, stream, w2, w2r);
    hipLaunchKernelGGL(k_w1r,     dim3(64),          dim3(256), 0, stream, w1, w1r);
    hipLaunchKernelGGL(k_conv1,   dim3(32, 2, B_),   dim3(256), 0, stream, seq, aa_emb, w1r, b1, y1t);
    hipLaunchKernelGGL(k_v,       dim3(8, B_),       dim3(256), 0, stream, goidx, go_table, attn_w, v);
    hipLaunchKernelGGL(k_conv2,   dim3(16, 2, B_),   dim3(256), 0, stream, y1t, w2r, b2, v, E, energies);
    hipLaunchKernelGGL(k_softmax, dim3(B_),          dim3(256), 0, stream, energies, attn);
    hipLaunchKernelGGL(k_ctx,     dim3(64, B_),      dim3(256), 0, stream, E, attn, out);
}